// Round 6
// baseline (497.997 us; speedup 1.0000x reference)
//
#include <hip/hip_runtime.h>
#include <cstdint>
#include <cstddef>

// ---------------- common types / helpers ----------------
typedef __attribute__((ext_vector_type(8))) short bf16x8;
typedef __attribute__((ext_vector_type(4))) float f32x4;
typedef __attribute__((ext_vector_type(16))) float f32x16;

#define S_LEN 2048
#define SCALE2 0.10411754f   // 192^-0.5 * log2(e)

__device__ __forceinline__ ushort f2bf(float f) {
  uint32_t u = __float_as_uint(f);
  u = (u + 0x7FFFu + ((u >> 16) & 1u)) >> 16;
  return (ushort)u;
}
__device__ __forceinline__ float bf2f(ushort u) {
  return __uint_as_float(((uint32_t)u) << 16);
}

typedef __attribute__((address_space(1))) void GV;
typedef __attribute__((address_space(3))) void LV;
__device__ __forceinline__ void gload16(const void* g, void* l) {
  __builtin_amdgcn_global_load_lds((GV*)g, (LV*)l, 16, 0, 0);
}

__device__ __forceinline__ void store_out(float* p, float v) { *p = v; }
__device__ __forceinline__ void store_out(ushort* p, float v) { *p = f2bf(v); }

// ---------------- fp32 -> bf16 convert ----------------
__global__ void k_f32_to_bf16(const float* __restrict__ in, ushort* __restrict__ out, int n4) {
  int i = blockIdx.x * blockDim.x + threadIdx.x;
  int stride = gridDim.x * blockDim.x;
  for (; i < n4; i += stride) {
    float4 v = reinterpret_cast<const float4*>(in)[i];
    ushort4 o;
    o.x = f2bf(v.x); o.y = f2bf(v.y); o.z = f2bf(v.z); o.w = f2bf(v.w);
    reinterpret_cast<ushort4*>(out)[i] = o;
  }
}

// ---------------- fp32 (R,C) -> bf16 transposed (C,R) ----------------
__global__ void k_transpose_f32_bf16(const float* __restrict__ in, ushort* __restrict__ out,
                                     int R, int C) {
  __shared__ float tile[32][33];
  int c0 = blockIdx.x * 32, r0 = blockIdx.y * 32;
  int tx = threadIdx.x, ty = threadIdx.y;
#pragma unroll
  for (int i = 0; i < 32; i += 8) {
    int r = r0 + ty + i, c = c0 + tx;
    if (r < R && c < C) tile[ty + i][tx] = in[(size_t)r * C + c];
  }
  __syncthreads();
#pragma unroll
  for (int i = 0; i < 32; i += 8) {
    int c = c0 + ty + i, r = r0 + tx;
    if (r < R && c < C) out[(size_t)c * R + r] = f2bf(tile[tx][ty + i]);
  }
}

// ---------------- bf16 GEMM: C[M,Nreal] = A[M,K] * Bt[N,K]^T ----------------
template <typename OUT>
__global__ __launch_bounds__(256) void k_gemm(const ushort* __restrict__ A,
                                              const ushort* __restrict__ Bt,
                                              OUT* __restrict__ C, int K, int Nreal) {
  __shared__ ushort As[128 * 32];
  __shared__ ushort Bs[128 * 32];
  const int t = threadIdx.x, lane = t & 63, w = t >> 6;
  // XCD-aware bijective swizzle (nwg % 8 == 0 for all our grids)
  const int nwg = gridDim.x * gridDim.y;
  const int wg = blockIdx.y * gridDim.x + blockIdx.x;
  const int swz = (wg & 7) * (nwg >> 3) + (wg >> 3);
  const int m0 = (swz / gridDim.x) * 128, n0 = (swz % gridDim.x) * 128;
  const int wm = (w >> 1) * 64, wn = (w & 1) * 64;
  const int g = lane >> 4, q = lane & 15;
  f32x4 acc[4][4] = {};
  for (int kt = 0; kt < K; kt += 32) {
#pragma unroll
    for (int i = 0; i < 2; i++) {
      int idx = i * 256 + t;
      gload16(A + (size_t)(m0 + (idx >> 2)) * K + kt + (idx & 3) * 8,
              (char*)As + (size_t)(i * 256 + (w << 6)) * 16);
      gload16(Bt + (size_t)(n0 + (idx >> 2)) * K + kt + (idx & 3) * 8,
              (char*)Bs + (size_t)(i * 256 + (w << 6)) * 16);
    }
    __syncthreads();
    bf16x8 af[4], bfr[4];
#pragma unroll
    for (int mi = 0; mi < 4; mi++) af[mi] = *(const bf16x8*)(As + (wm + 16 * mi + q) * 32 + 8 * g);
#pragma unroll
    for (int ni = 0; ni < 4; ni++) bfr[ni] = *(const bf16x8*)(Bs + (wn + 16 * ni + q) * 32 + 8 * g);
#pragma unroll
    for (int mi = 0; mi < 4; mi++)
#pragma unroll
      for (int ni = 0; ni < 4; ni++)
        acc[mi][ni] = __builtin_amdgcn_mfma_f32_16x16x32_bf16(af[mi], bfr[ni], acc[mi][ni], 0, 0, 0);
    __syncthreads();
  }
#pragma unroll
  for (int mi = 0; mi < 4; mi++)
#pragma unroll
    for (int ni = 0; ni < 4; ni++) {
      int col = n0 + wn + 16 * ni + q;
      if (col < Nreal) {
        int row = m0 + wm + 16 * mi + 4 * g;
#pragma unroll
        for (int r = 0; r < 4; r++)
          store_out(&C[(size_t)(row + r) * Nreal + col], acc[mi][ni][r]);
      }
    }
}

// ---------------- kv GEMM: writes k_nope into kbuf[b][h][s][192] cols 0..127
// and V into vT[b][h][d][2048]. M=4096 tokens, K=512, N=4096. ----------------
__global__ __launch_bounds__(256) void k_gemm_kv(const ushort* __restrict__ A,
                                                 const ushort* __restrict__ Bt,
                                                 ushort* __restrict__ kbuf,
                                                 ushort* __restrict__ vT, int K) {
  __shared__ ushort As[128 * 32];
  __shared__ ushort Bs[128 * 32];
  const int t = threadIdx.x, lane = t & 63, w = t >> 6;
  const int nwg = gridDim.x * gridDim.y;
  const int wg = blockIdx.y * gridDim.x + blockIdx.x;
  const int swz = (wg & 7) * (nwg >> 3) + (wg >> 3);
  const int m0 = (swz / gridDim.x) * 128, n0 = (swz % gridDim.x) * 128;
  const int wm = (w >> 1) * 64, wn = (w & 1) * 64;
  const int g = lane >> 4, q = lane & 15;
  f32x4 acc[4][4] = {};
  for (int kt = 0; kt < K; kt += 32) {
#pragma unroll
    for (int i = 0; i < 2; i++) {
      int idx = i * 256 + t;
      gload16(A + (size_t)(m0 + (idx >> 2)) * K + kt + (idx & 3) * 8,
              (char*)As + (size_t)(i * 256 + (w << 6)) * 16);
      gload16(Bt + (size_t)(n0 + (idx >> 2)) * K + kt + (idx & 3) * 8,
              (char*)Bs + (size_t)(i * 256 + (w << 6)) * 16);
    }
    __syncthreads();
    bf16x8 af[4], bfr[4];
#pragma unroll
    for (int mi = 0; mi < 4; mi++) af[mi] = *(const bf16x8*)(As + (wm + 16 * mi + q) * 32 + 8 * g);
#pragma unroll
    for (int ni = 0; ni < 4; ni++) bfr[ni] = *(const bf16x8*)(Bs + (wn + 16 * ni + q) * 32 + 8 * g);
#pragma unroll
    for (int mi = 0; mi < 4; mi++)
#pragma unroll
      for (int ni = 0; ni < 4; ni++)
        acc[mi][ni] = __builtin_amdgcn_mfma_f32_16x16x32_bf16(af[mi], bfr[ni], acc[mi][ni], 0, 0, 0);
    __syncthreads();
  }
#pragma unroll
  for (int mi = 0; mi < 4; mi++)
#pragma unroll
    for (int ni = 0; ni < 4; ni++) {
      int col = n0 + wn + 16 * ni + q;     // 0..4095
      int hh = col >> 8, jj = col & 255;
      int row0 = m0 + wm + 16 * mi + 4 * g;
#pragma unroll
      for (int r = 0; r < 4; r++) {
        int tok = row0 + r;
        int bb = tok >> 11, ss = tok & 2047;
        ushort v = f2bf(acc[mi][ni][r]);
        if (jj < 128)
          kbuf[((size_t)(bb * 16 + hh) * 2048 + ss) * 192 + jj] = v;
        else
          vT[((size_t)(bb * 16 + hh) * 128 + (jj - 128)) * 2048 + ss] = v;
      }
    }
}

// ---------------- RMSNorm (fp32 in, bf16 out) ----------------
__global__ void k_rmsnorm_bf16(const float* __restrict__ in, const float* __restrict__ w,
                               ushort* __restrict__ out, int D) {
  int row = blockIdx.x;
  const float* x = in + (size_t)row * D;
  ushort* o = out + (size_t)row * D;
  float ss = 0.f;
  for (int i = threadIdx.x; i < D; i += 256) { float v = x[i]; ss += v * v; }
#pragma unroll
  for (int m = 1; m < 64; m <<= 1) ss += __shfl_xor(ss, m);
  __shared__ float red[4];
  if ((threadIdx.x & 63) == 0) red[threadIdx.x >> 6] = ss;
  __syncthreads();
  float tot = red[0] + red[1] + red[2] + red[3];
  float sc = rsqrtf(tot / (float)D + 1e-6f);
  for (int i = threadIdx.x; i < D; i += 256) o[i] = f2bf(x[i] * sc * w[i]);
}

// ---------------- kv RMSNorm (512) + k_pe rope broadcast into kbuf ----------------
__global__ void k_kvnorm_rope(const float* __restrict__ ckv, const float* __restrict__ w,
                              const float* __restrict__ cosT, const float* __restrict__ sinT,
                              ushort* __restrict__ ckvn, ushort* __restrict__ kbuf) {
  int tok = blockIdx.x, b = tok >> 11, s = tok & 2047;
  const float* x = ckv + (size_t)tok * 576;
  float ss = 0.f;
  for (int i = threadIdx.x; i < 512; i += 256) { float v = x[i]; ss += v * v; }
#pragma unroll
  for (int m = 1; m < 64; m <<= 1) ss += __shfl_xor(ss, m);
  __shared__ float red[4];
  if ((threadIdx.x & 63) == 0) red[threadIdx.x >> 6] = ss;
  __syncthreads();
  float tot = red[0] + red[1] + red[2] + red[3];
  float sc = rsqrtf(tot / 512.f + 1e-6f);
  for (int i = threadIdx.x; i < 512; i += 256) ckvn[(size_t)tok * 512 + i] = f2bf(x[i] * sc * w[i]);
  if (threadIdx.x < 32) {
    int i = threadIdx.x;
    float xr = x[512 + 2 * i], xi = x[512 + 2 * i + 1];
    float c = cosT[s * 32 + i], sn = sinT[s * 32 + i];
    uint32_t lo = f2bf(xr * c - xi * sn);
    uint32_t hi = f2bf(xr * sn + xi * c);
    uint32_t pk = lo | (hi << 16);
#pragma unroll
    for (int h = 0; h < 16; ++h)
      *(uint32_t*)(kbuf + ((size_t)(b * 16 + h) * 2048 + s) * 192 + 128 + 2 * i) = pk;
  }
}

// ---------------- q rope, in-place on bf16 q (4096, 16, 192) ----------------
__global__ void k_qrope(ushort* __restrict__ qb, const float* __restrict__ cosT,
                        const float* __restrict__ sinT) {
  int tok = blockIdx.x, s = tok & (S_LEN - 1);
  for (int pp = threadIdx.x; pp < 512; pp += 256) {
    int h = pp >> 5, i = pp & 31;
    ushort* base = qb + ((size_t)tok * 16 + h) * 192 + 128;
    float xr = bf2f(base[2 * i]), xi = bf2f(base[2 * i + 1]);
    float c = cosT[s * 32 + i], sn = sinT[s * 32 + i];
    base[2 * i] = f2bf(xr * c - xi * sn);
    base[2 * i + 1] = f2bf(xr * sn + xi * c);
  }
}

// ---------------- causal flash attention: swapped-QK^T, 32x32 MFMA ----------------
// grid 512 (1-D), 4 waves/block, ~2 blocks/CU. Block id: qt = 15-(id>>5)
// (heavy tiles dispatch first -> greedy balancing), bh = id&31.
// Each block: one 128-row q-tile, wave w owns 32 rows.
// Swapped QK: S-tile = mfma(A=K, B=Q) -> lane holds one q-row (col=lq) at
// kk = (r&3)+8(r>>2)+4*hi. Softmax in-register (1 shfl_xor(32) per reduce),
// defer-max (T13, THR=8 in exp2 domain). P rebuilt in-register -> PV B-operand
// of O^T = V^T * P^T. LDS: linear-chunk layouts + chunk-XOR swizzle.
__global__ __launch_bounds__(256, 3) void k_attn6(const ushort* __restrict__ qb,
                                                  const ushort* __restrict__ kb,
                                                  const ushort* __restrict__ vT,
                                                  ushort* __restrict__ aout) {
  const int id = blockIdx.x;
  const int qt = 15 - (id >> 5);
  const int bh = id & 31;
  const int h = bh & 15, b = bh >> 4;

  const int t = threadIdx.x, lane = t & 63, w = t >> 6;
  const int lq = lane & 31, hi = lane >> 5;
  const int kx = (lq >> 3) & 3;              // read-side chunk XOR

  __shared__ ushort Ks[2][6656];   // 32 rows x 25 chunks (1 pad chunk/row) + tail
  __shared__ ushort Vs[2][5120];   // 128 rows x 5 chunks (1 pad chunk/row)

  const ushort* kh = kb + (size_t)(b * 16 + h) * (2048 * 192);
  const ushort* vh = vT + (size_t)(b * 16 + h) * (128 * 2048);

  auto stage = [&](int k0, int bi) {
    // K: 32 x 192 -> 800 slots of 16B (25/row, slot 24 = pad), 13 wave-iters
#pragma unroll
    for (int it = 0; it < 4; ++it) {
      int ii = it * 4 + w;
      if (ii < 13) {
        unsigned s = ii * 64 + lane;
        int r = s / 25, cs = s - r * 25;
        if (r > 31) { r = 31; cs = 24; }
        int cg = cs ^ ((r >> 3) & 3);        // inverse-swizzled source chunk
        if (cg > 23) cg = 0;                 // pad slots load dummy
        gload16(kh + (size_t)(k0 + r) * 192 + cg * 8, (char*)&Ks[bi][0] + ii * 1024);
      }
    }
    // V: 128 x 32 -> 640 slots (5/row, slot 4 = pad), 10 wave-iters
#pragma unroll
    for (int it = 0; it < 3; ++it) {
      int ii = it * 4 + w;
      if (ii < 10) {
        unsigned s = ii * 64 + lane;
        int r = s / 5, cs = s - r * 5;
        int cg = cs ^ ((r >> 3) & 3);
        if (cg > 3) cg = 0;
        gload16(vh + (size_t)r * 2048 + k0 + cg * 8, (char*)&Vs[bi][0] + ii * 1024);
      }
    }
  };

  const int q0 = qt * 128;
  const int q0w = q0 + 32 * w;               // wave's lowest q-row
  const int qg = q0w + lq;                   // this lane's q-row
  const int nkt = qt * 4 + 4;

  // Q fragments: lane reads its q-row, d = 16s + 8*hi .. +7
  bf16x8 qf[12];
  {
    const ushort* qp = qb + ((size_t)(b * 2048 + qg) * 16 + h) * 192 + 8 * hi;
#pragma unroll
    for (int s = 0; s < 12; ++s) qf[s] = *(const bf16x8*)(qp + 16 * s);
  }

  f32x16 oacc[4];
#pragma unroll
  for (int db = 0; db < 4; ++db)
#pragma unroll
    for (int r = 0; r < 16; ++r) oacc[db][r] = 0.f;
  float m = -1e30f, l = 0.f;

  stage(0, 0);
  asm volatile("s_waitcnt vmcnt(0)" ::: "memory");
  __syncthreads();
  int cur = 0;

  for (int kt = 0; kt < nkt; ++kt) {
    const int k0 = kt * 32;
    if (kt + 1 < nkt) stage((kt + 1) * 32, cur ^ 1);
    const ushort* KB = &Ks[cur][0];
    const ushort* VB = &Vs[cur][0];
    if (k0 <= q0w + 31) {
      // ---- QK^T (swapped): S[kk][q] over d=192 in 12 slabs ----
      f32x16 sacc;
#pragma unroll
      for (int r = 0; r < 16; ++r) sacc[r] = 0.f;
      __builtin_amdgcn_s_setprio(1);
#pragma unroll
      for (int s = 0; s < 12; ++s) {
        bf16x8 kf = *(const bf16x8*)(KB + lq * 200 + (((2 * s + hi) ^ kx) << 3));
        sacc = __builtin_amdgcn_mfma_f32_32x32x16_bf16(kf, qf[s], sacc, 0, 0, 0);
      }
      __builtin_amdgcn_s_setprio(0);
      float sv[16];
#pragma unroll
      for (int r = 0; r < 16; ++r) sv[r] = sacc[r];
      if (k0 + 31 > q0w) {                   // diagonal region: causal mask
#pragma unroll
        for (int r = 0; r < 16; ++r)
          if (k0 + (r & 3) + 8 * (r >> 2) + 4 * hi > qg) sv[r] = -1e30f;
      }
      // ---- in-register online softmax with defer-max (THR=8, exp2 domain) ----
      float pmax = sv[0];
#pragma unroll
      for (int r = 1; r < 16; ++r) pmax = fmaxf(pmax, sv[r]);
      pmax = fmaxf(pmax, __shfl_xor(pmax, 32));
      float smax = pmax * SCALE2;
      if (!__all(smax - m <= 8.0f)) {
        float mnew = fmaxf(m, smax);
        float a = exp2f(m - mnew);
        l *= a;
#pragma unroll
        for (int db = 0; db < 4; ++db)
#pragma unroll
          for (int r = 0; r < 16; ++r) oacc[db][r] *= a;
        m = mnew;
      }
      float e[16]; float sum = 0.f;
#pragma unroll
      for (int r = 0; r < 16; ++r) { e[r] = exp2f(sv[r] * SCALE2 - m); sum += e[r]; }
      sum += __shfl_xor(sum, 32);
      l += sum;
      // ---- P -> bf16 PV B-fragments (4 half-swaps via shfl_xor 32) ----
      uint32_t pk[8];
#pragma unroll
      for (int i = 0; i < 8; ++i)
        pk[i] = (uint32_t)f2bf(e[2 * i]) | ((uint32_t)f2bf(e[2 * i + 1]) << 16);
      uint32_t sw[8];
#pragma unroll
      for (int i = 0; i < 8; ++i) sw[i] = (uint32_t)__shfl_xor((int)pk[i], 32);
      union { uint32_t u[4]; bf16x8 v; } p0, p1;
      p0.u[0] = hi ? sw[2] : pk[0];
      p0.u[1] = hi ? sw[3] : pk[1];
      p0.u[2] = hi ? pk[2] : sw[0];
      p0.u[3] = hi ? pk[3] : sw[1];
      p1.u[0] = hi ? sw[6] : pk[4];
      p1.u[1] = hi ? sw[7] : pk[5];
      p1.u[2] = hi ? pk[6] : sw[4];
      p1.u[3] = hi ? pk[7] : sw[5];
      // ---- PV: O^T[d][q] += V^T[d][k] P^T[k][q] ----
      __builtin_amdgcn_s_setprio(1);
#pragma unroll
      for (int db = 0; db < 4; ++db) {
        bf16x8 vf0 = *(const bf16x8*)(VB + (32 * db + lq) * 40 + ((hi ^ kx) << 3));
        bf16x8 vf1 = *(const bf16x8*)(VB + (32 * db + lq) * 40 + (((2 + hi) ^ kx) << 3));
        oacc[db] = __builtin_amdgcn_mfma_f32_32x32x16_bf16(vf0, p0.v, oacc[db], 0, 0, 0);
        oacc[db] = __builtin_amdgcn_mfma_f32_32x32x16_bf16(vf1, p1.v, oacc[db], 0, 0, 0);
      }
      __builtin_amdgcn_s_setprio(0);
    }
    asm volatile("s_waitcnt vmcnt(0) lgkmcnt(0)" ::: "memory");
    __syncthreads();
    cur ^= 1;
  }

  // ---- epilogue: normalize + store (pairs of consecutive d as u32) ----
  float inv = 1.f / l;
  ushort* op = aout + ((size_t)(b * 2048 + qg)) * 2048 + h * 128 + 4 * hi;
#pragma unroll
  for (int db = 0; db < 4; ++db)
#pragma unroll
    for (int i = 0; i < 8; ++i) {
      uint32_t u = (uint32_t)f2bf(oacc[db][2 * i] * inv) |
                   ((uint32_t)f2bf(oacc[db][2 * i + 1] * inv) << 16);
      int dbase = 32 * db + (i & 1) * 2 + (i >> 1) * 8;
      *(uint32_t*)(op + dbase) = u;
    }
}

// ---------------- launcher ----------------
extern "C" void kernel_launch(void* const* d_in, const int* in_sizes, int n_in,
                              void* d_out, int out_size, void* d_ws, size_t ws_size,
                              hipStream_t stream) {
  const float* x = (const float*)d_in[0];
  const float* fcos = (const float*)d_in[1];
  const float* fsin = (const float*)d_in[2];
  const float* wq_a = (const float*)d_in[3];
  const float* qnw = (const float*)d_in[4];
  const float* wq_b = (const float*)d_in[5];
  const float* wkv_a = (const float*)d_in[6];
  const float* kvnw = (const float*)d_in[7];
  const float* wkv_b = (const float*)d_in[8];
  const float* wo = (const float*)d_in[9];
  float* out = (float*)d_out;

  char* ws = (char*)d_ws;
  size_t off = 0;
  auto alloc = [&](size_t bytes) -> char* {
    char* p = ws + off;
    off += (bytes + 255) & ~(size_t)255;
    return p;
  };
  ushort* xb     = (ushort*)alloc(4096ull * 2048 * 2);
  ushort* wqa_t  = (ushort*)alloc(1536ull * 2048 * 2);   // } these three (18.3MB)
  ushort* wqb_t  = (ushort*)alloc(3072ull * 1536 * 2);   // } are dead after GEMM2
  ushort* wkva_t = (ushort*)alloc(640ull * 2048 * 2);    // } -> reused as vT (16.8MB)
  ushort* wkvb_t = (ushort*)alloc(4096ull * 512 * 2);
  ushort* wo_t   = (ushort*)alloc(2048ull * 2048 * 2);
  float*  cq     = (float*)alloc(4096ull * 1536 * 4);
  float*  ckv    = (float*)alloc(4096ull * 576 * 4);
  ushort* cqn    = (ushort*)alloc(4096ull * 1536 * 2);
  ushort* ckvn   = (ushort*)alloc(4096ull * 512 * 2);
  ushort* kbuf   = (ushort*)alloc(2ull * 16 * 2048 * 192 * 2);
  ushort* qbuf   = (ushort*)cq;     // reuse: cq dead after rmsnorm (25.2MB each)
  ushort* aout   = xb;              // reuse: x dead after GEMM1a/1b
  ushort* vT     = wqa_t;           // reuse: wqa_t+wqb_t+wkva_t dead after GEMM2

  dim3 tb(32, 8);
  k_f32_to_bf16<<<2048, 256, 0, stream>>>(x, xb, 4096 * 2048 / 4);
  k_transpose_f32_bf16<<<dim3(48, 64), tb, 0, stream>>>(wq_a, wqa_t, 2048, 1536);
  k_transpose_f32_bf16<<<dim3(18, 64), tb, 0, stream>>>(wkv_a, wkva_t, 2048, 576);
  k_transpose_f32_bf16<<<dim3(96, 48), tb, 0, stream>>>(wq_b, wqb_t, 1536, 3072);
  k_transpose_f32_bf16<<<dim3(128, 16), tb, 0, stream>>>(wkv_b, wkvb_t, 512, 4096);
  k_transpose_f32_bf16<<<dim3(64, 64), tb, 0, stream>>>(wo, wo_t, 2048, 2048);

  // cq = xb @ wq_a  (M=4096, K=2048, N=1536)
  k_gemm<float><<<dim3(12, 32), 256, 0, stream>>>(xb, wqa_t, cq, 2048, 1536);
  // ckv = xb @ wkv_a (N padded 640, Nreal=576)
  k_gemm<float><<<dim3(5, 32), 256, 0, stream>>>(xb, wkva_t, ckv, 2048, 576);

  k_rmsnorm_bf16<<<4096, 256, 0, stream>>>(cq, qnw, cqn, 1536);
  k_kvnorm_rope<<<4096, 256, 0, stream>>>(ckv, kvnw, fcos, fsin, ckvn, kbuf);

  // q = cqn @ wq_b (K=1536, N=3072), bf16 out  (last reader of wqb_t)
  k_gemm<ushort><<<dim3(24, 32), 256, 0, stream>>>(cqn, wqb_t, qbuf, 1536, 3072);
  k_qrope<<<4096, 256, 0, stream>>>(qbuf, fcos, fsin);

  // kv = ckvn @ wkv_b (K=512, N=4096) -> kbuf (nope) + vT (V transposed)
  k_gemm_kv<<<dim3(32, 32), 256, 0, stream>>>(ckvn, wkvb_t, kbuf, vT, 512);

  k_attn6<<<dim3(512), 256, 0, stream>>>(qbuf, kbuf, vT, aout);

  // out = aout @ wo (K=2048, N=2048), fp32 out
  k_gemm<float><<<dim3(16, 32), 256, 0, stream>>>(aout, wo_t, out, 2048, 2048);
}

// Round 7
// 429.316 us; speedup vs baseline: 1.1600x; 1.1600x over previous
//
#include <hip/hip_runtime.h>
#include <cstdint>
#include <cstddef>

// ---------------- common types / helpers ----------------
typedef __attribute__((ext_vector_type(8))) short bf16x8;
typedef __attribute__((ext_vector_type(4))) float f32x4;
typedef __attribute__((ext_vector_type(16))) float f32x16;

#define S_LEN 2048
#define SCALE2 0.10411754f   // 192^-0.5 * log2(e)

__device__ __forceinline__ ushort f2bf(float f) {
  uint32_t u = __float_as_uint(f);
  u = (u + 0x7FFFu + ((u >> 16) & 1u)) >> 16;
  return (ushort)u;
}
__device__ __forceinline__ float bf2f(ushort u) {
  return __uint_as_float(((uint32_t)u) << 16);
}

typedef __attribute__((address_space(1))) void GV;
typedef __attribute__((address_space(3))) void LV;
__device__ __forceinline__ void gload16(const void* g, void* l) {
  __builtin_amdgcn_global_load_lds((GV*)g, (LV*)l, 16, 0, 0);
}

__device__ __forceinline__ void store_out(float* p, float v) { *p = v; }
__device__ __forceinline__ void store_out(ushort* p, float v) { *p = f2bf(v); }

// ---------------- fp32 -> bf16 convert ----------------
__global__ void k_f32_to_bf16(const float* __restrict__ in, ushort* __restrict__ out, int n4) {
  int i = blockIdx.x * blockDim.x + threadIdx.x;
  int stride = gridDim.x * blockDim.x;
  for (; i < n4; i += stride) {
    float4 v = reinterpret_cast<const float4*>(in)[i];
    ushort4 o;
    o.x = f2bf(v.x); o.y = f2bf(v.y); o.z = f2bf(v.z); o.w = f2bf(v.w);
    reinterpret_cast<ushort4*>(out)[i] = o;
  }
}

// ---------------- fp32 (R,C) -> bf16 transposed (C,R) ----------------
__global__ void k_transpose_f32_bf16(const float* __restrict__ in, ushort* __restrict__ out,
                                     int R, int C) {
  __shared__ float tile[32][33];
  int c0 = blockIdx.x * 32, r0 = blockIdx.y * 32;
  int tx = threadIdx.x, ty = threadIdx.y;
#pragma unroll
  for (int i = 0; i < 32; i += 8) {
    int r = r0 + ty + i, c = c0 + tx;
    if (r < R && c < C) tile[ty + i][tx] = in[(size_t)r * C + c];
  }
  __syncthreads();
#pragma unroll
  for (int i = 0; i < 32; i += 8) {
    int c = c0 + ty + i, r = r0 + tx;
    if (r < R && c < C) out[(size_t)c * R + r] = f2bf(tile[tx][ty + i]);
  }
}

// ---------------- bf16 GEMM: C[M,Nreal] = A[M,K] * Bt[N,K]^T ----------------
template <typename OUT>
__global__ __launch_bounds__(256) void k_gemm(const ushort* __restrict__ A,
                                              const ushort* __restrict__ Bt,
                                              OUT* __restrict__ C, int K, int Nreal) {
  __shared__ ushort As[128 * 32];
  __shared__ ushort Bs[128 * 32];
  const int t = threadIdx.x, lane = t & 63, w = t >> 6;
  // XCD-aware bijective swizzle (nwg % 8 == 0 for all our grids)
  const int nwg = gridDim.x * gridDim.y;
  const int wg = blockIdx.y * gridDim.x + blockIdx.x;
  const int swz = (wg & 7) * (nwg >> 3) + (wg >> 3);
  const int m0 = (swz / gridDim.x) * 128, n0 = (swz % gridDim.x) * 128;
  const int wm = (w >> 1) * 64, wn = (w & 1) * 64;
  const int g = lane >> 4, q = lane & 15;
  f32x4 acc[4][4] = {};
  for (int kt = 0; kt < K; kt += 32) {
#pragma unroll
    for (int i = 0; i < 2; i++) {
      int idx = i * 256 + t;
      gload16(A + (size_t)(m0 + (idx >> 2)) * K + kt + (idx & 3) * 8,
              (char*)As + (size_t)(i * 256 + (w << 6)) * 16);
      gload16(Bt + (size_t)(n0 + (idx >> 2)) * K + kt + (idx & 3) * 8,
              (char*)Bs + (size_t)(i * 256 + (w << 6)) * 16);
    }
    __syncthreads();
    bf16x8 af[4], bfr[4];
#pragma unroll
    for (int mi = 0; mi < 4; mi++) af[mi] = *(const bf16x8*)(As + (wm + 16 * mi + q) * 32 + 8 * g);
#pragma unroll
    for (int ni = 0; ni < 4; ni++) bfr[ni] = *(const bf16x8*)(Bs + (wn + 16 * ni + q) * 32 + 8 * g);
#pragma unroll
    for (int mi = 0; mi < 4; mi++)
#pragma unroll
      for (int ni = 0; ni < 4; ni++)
        acc[mi][ni] = __builtin_amdgcn_mfma_f32_16x16x32_bf16(af[mi], bfr[ni], acc[mi][ni], 0, 0, 0);
    __syncthreads();
  }
#pragma unroll
  for (int mi = 0; mi < 4; mi++)
#pragma unroll
    for (int ni = 0; ni < 4; ni++) {
      int col = n0 + wn + 16 * ni + q;
      if (col < Nreal) {
        int row = m0 + wm + 16 * mi + 4 * g;
#pragma unroll
        for (int r = 0; r < 4; r++)
          store_out(&C[(size_t)(row + r) * Nreal + col], acc[mi][ni][r]);
      }
    }
}

// ---------------- kv GEMM: writes k_nope into kbuf[b][h][s][192] cols 0..127
// and V into vT[b][h][d][2048]. M=4096 tokens, K=512, N=4096. ----------------
__global__ __launch_bounds__(256) void k_gemm_kv(const ushort* __restrict__ A,
                                                 const ushort* __restrict__ Bt,
                                                 ushort* __restrict__ kbuf,
                                                 ushort* __restrict__ vT, int K) {
  __shared__ ushort As[128 * 32];
  __shared__ ushort Bs[128 * 32];
  const int t = threadIdx.x, lane = t & 63, w = t >> 6;
  const int nwg = gridDim.x * gridDim.y;
  const int wg = blockIdx.y * gridDim.x + blockIdx.x;
  const int swz = (wg & 7) * (nwg >> 3) + (wg >> 3);
  const int m0 = (swz / gridDim.x) * 128, n0 = (swz % gridDim.x) * 128;
  const int wm = (w >> 1) * 64, wn = (w & 1) * 64;
  const int g = lane >> 4, q = lane & 15;
  f32x4 acc[4][4] = {};
  for (int kt = 0; kt < K; kt += 32) {
#pragma unroll
    for (int i = 0; i < 2; i++) {
      int idx = i * 256 + t;
      gload16(A + (size_t)(m0 + (idx >> 2)) * K + kt + (idx & 3) * 8,
              (char*)As + (size_t)(i * 256 + (w << 6)) * 16);
      gload16(Bt + (size_t)(n0 + (idx >> 2)) * K + kt + (idx & 3) * 8,
              (char*)Bs + (size_t)(i * 256 + (w << 6)) * 16);
    }
    __syncthreads();
    bf16x8 af[4], bfr[4];
#pragma unroll
    for (int mi = 0; mi < 4; mi++) af[mi] = *(const bf16x8*)(As + (wm + 16 * mi + q) * 32 + 8 * g);
#pragma unroll
    for (int ni = 0; ni < 4; ni++) bfr[ni] = *(const bf16x8*)(Bs + (wn + 16 * ni + q) * 32 + 8 * g);
#pragma unroll
    for (int mi = 0; mi < 4; mi++)
#pragma unroll
      for (int ni = 0; ni < 4; ni++)
        acc[mi][ni] = __builtin_amdgcn_mfma_f32_16x16x32_bf16(af[mi], bfr[ni], acc[mi][ni], 0, 0, 0);
    __syncthreads();
  }
#pragma unroll
  for (int mi = 0; mi < 4; mi++)
#pragma unroll
    for (int ni = 0; ni < 4; ni++) {
      int col = n0 + wn + 16 * ni + q;     // 0..4095
      int hh = col >> 8, jj = col & 255;
      int row0 = m0 + wm + 16 * mi + 4 * g;
#pragma unroll
      for (int r = 0; r < 4; r++) {
        int tok = row0 + r;
        int bb = tok >> 11, ss = tok & 2047;
        ushort v = f2bf(acc[mi][ni][r]);
        if (jj < 128)
          kbuf[((size_t)(bb * 16 + hh) * 2048 + ss) * 192 + jj] = v;
        else
          vT[((size_t)(bb * 16 + hh) * 128 + (jj - 128)) * 2048 + ss] = v;
      }
    }
}

// ---------------- RMSNorm (fp32 in, bf16 out) ----------------
__global__ void k_rmsnorm_bf16(const float* __restrict__ in, const float* __restrict__ w,
                               ushort* __restrict__ out, int D) {
  int row = blockIdx.x;
  const float* x = in + (size_t)row * D;
  ushort* o = out + (size_t)row * D;
  float ss = 0.f;
  for (int i = threadIdx.x; i < D; i += 256) { float v = x[i]; ss += v * v; }
#pragma unroll
  for (int m = 1; m < 64; m <<= 1) ss += __shfl_xor(ss, m);
  __shared__ float red[4];
  if ((threadIdx.x & 63) == 0) red[threadIdx.x >> 6] = ss;
  __syncthreads();
  float tot = red[0] + red[1] + red[2] + red[3];
  float sc = rsqrtf(tot / (float)D + 1e-6f);
  for (int i = threadIdx.x; i < D; i += 256) o[i] = f2bf(x[i] * sc * w[i]);
}

// ---------------- kv RMSNorm (512) + k_pe rope broadcast into kbuf ----------------
__global__ void k_kvnorm_rope(const float* __restrict__ ckv, const float* __restrict__ w,
                              const float* __restrict__ cosT, const float* __restrict__ sinT,
                              ushort* __restrict__ ckvn, ushort* __restrict__ kbuf) {
  int tok = blockIdx.x, b = tok >> 11, s = tok & 2047;
  const float* x = ckv + (size_t)tok * 576;
  float ss = 0.f;
  for (int i = threadIdx.x; i < 512; i += 256) { float v = x[i]; ss += v * v; }
#pragma unroll
  for (int m = 1; m < 64; m <<= 1) ss += __shfl_xor(ss, m);
  __shared__ float red[4];
  if ((threadIdx.x & 63) == 0) red[threadIdx.x >> 6] = ss;
  __syncthreads();
  float tot = red[0] + red[1] + red[2] + red[3];
  float sc = rsqrtf(tot / 512.f + 1e-6f);
  for (int i = threadIdx.x; i < 512; i += 256) ckvn[(size_t)tok * 512 + i] = f2bf(x[i] * sc * w[i]);
  if (threadIdx.x < 32) {
    int i = threadIdx.x;
    float xr = x[512 + 2 * i], xi = x[512 + 2 * i + 1];
    float c = cosT[s * 32 + i], sn = sinT[s * 32 + i];
    uint32_t lo = f2bf(xr * c - xi * sn);
    uint32_t hi = f2bf(xr * sn + xi * c);
    uint32_t pk = lo | (hi << 16);
#pragma unroll
    for (int h = 0; h < 16; ++h)
      *(uint32_t*)(kbuf + ((size_t)(b * 16 + h) * 2048 + s) * 192 + 128 + 2 * i) = pk;
  }
}

// ---------------- q rope, in-place on bf16 q (4096, 16, 192) ----------------
__global__ void k_qrope(ushort* __restrict__ qb, const float* __restrict__ cosT,
                        const float* __restrict__ sinT) {
  int tok = blockIdx.x, s = tok & (S_LEN - 1);
  for (int pp = threadIdx.x; pp < 512; pp += 256) {
    int h = pp >> 5, i = pp & 31;
    ushort* base = qb + ((size_t)tok * 16 + h) * 192 + 128;
    float xr = bf2f(base[2 * i]), xi = bf2f(base[2 * i + 1]);
    float c = cosT[s * 32 + i], sn = sinT[s * 32 + i];
    base[2 * i] = f2bf(xr * c - xi * sn);
    base[2 * i + 1] = f2bf(xr * sn + xi * c);
  }
}

// ---------------- causal flash attention: swapped-QK^T, 32x32 MFMA ----------------
// grid 512 (1-D), 4 waves/block, 2 blocks/CU. Block id: qt = 15-(id>>5)
// (heavy tiles dispatch first -> greedy balancing), bh = id&31.
// launch_bounds(256,2): do NOT force 3 waves/EU -- that caps VGPR at 84 and
// spills the 64-reg accumulator to scratch (R6 regression: +6MB writes, +23%).
__global__ __launch_bounds__(256, 2) void k_attn7(const ushort* __restrict__ qb,
                                                  const ushort* __restrict__ kb,
                                                  const ushort* __restrict__ vT,
                                                  ushort* __restrict__ aout) {
  const int id = blockIdx.x;
  const int qt = 15 - (id >> 5);
  const int bh = id & 31;
  const int h = bh & 15, b = bh >> 4;

  const int t = threadIdx.x, lane = t & 63, w = t >> 6;
  const int lq = lane & 31, hi = lane >> 5;
  const int kx = (lq >> 3) & 3;              // read-side chunk XOR

  __shared__ ushort Ks[2][6656];   // 32 rows x 25 chunks (1 pad chunk/row) + tail
  __shared__ ushort Vs[2][5120];   // 128 rows x 5 chunks (1 pad chunk/row)

  const ushort* kh = kb + (size_t)(b * 16 + h) * (2048 * 192);
  const ushort* vh = vT + (size_t)(b * 16 + h) * (128 * 2048);

  auto stage = [&](int k0, int bi) {
    // K: 32 x 192 -> 800 slots of 16B (25/row, slot 24 = pad), 13 wave-iters
#pragma unroll
    for (int it = 0; it < 4; ++it) {
      int ii = it * 4 + w;
      if (ii < 13) {
        unsigned s = ii * 64 + lane;
        int r = s / 25, cs = s - r * 25;
        if (r > 31) { r = 31; cs = 24; }
        int cg = cs ^ ((r >> 3) & 3);        // inverse-swizzled source chunk
        if (cg > 23) cg = 0;                 // pad slots load dummy
        gload16(kh + (size_t)(k0 + r) * 192 + cg * 8, (char*)&Ks[bi][0] + ii * 1024);
      }
    }
    // V: 128 x 32 -> 640 slots (5/row, slot 4 = pad), 10 wave-iters
#pragma unroll
    for (int it = 0; it < 3; ++it) {
      int ii = it * 4 + w;
      if (ii < 10) {
        unsigned s = ii * 64 + lane;
        int r = s / 5, cs = s - r * 5;
        int cg = cs ^ ((r >> 3) & 3);
        if (cg > 3) cg = 0;
        gload16(vh + (size_t)r * 2048 + k0 + cg * 8, (char*)&Vs[bi][0] + ii * 1024);
      }
    }
  };

  const int q0 = qt * 128;
  const int q0w = q0 + 32 * w;               // wave's lowest q-row
  const int qg = q0w + lq;                   // this lane's q-row
  const int nkt = qt * 4 + 4;

  // Q fragments: lane reads its q-row, d = 16s + 8*hi .. +7
  bf16x8 qf[12];
  {
    const ushort* qp = qb + ((size_t)(b * 2048 + qg) * 16 + h) * 192 + 8 * hi;
#pragma unroll
    for (int s = 0; s < 12; ++s) qf[s] = *(const bf16x8*)(qp + 16 * s);
  }

  f32x16 oacc[4];
#pragma unroll
  for (int db = 0; db < 4; ++db)
#pragma unroll
    for (int r = 0; r < 16; ++r) oacc[db][r] = 0.f;
  float m = -1e30f, l = 0.f;

  stage(0, 0);
  asm volatile("s_waitcnt vmcnt(0)" ::: "memory");
  __syncthreads();
  int cur = 0;

  for (int kt = 0; kt < nkt; ++kt) {
    const int k0 = kt * 32;
    if (kt + 1 < nkt) stage((kt + 1) * 32, cur ^ 1);
    const ushort* KB = &Ks[cur][0];
    const ushort* VB = &Vs[cur][0];
    if (k0 <= q0w + 31) {
      // ---- QK^T (swapped): S[kk][q] over d=192 in 12 slabs ----
      f32x16 sacc;
#pragma unroll
      for (int r = 0; r < 16; ++r) sacc[r] = 0.f;
      __builtin_amdgcn_s_setprio(1);
#pragma unroll
      for (int s = 0; s < 12; ++s) {
        bf16x8 kf = *(const bf16x8*)(KB + lq * 200 + (((2 * s + hi) ^ kx) << 3));
        sacc = __builtin_amdgcn_mfma_f32_32x32x16_bf16(kf, qf[s], sacc, 0, 0, 0);
      }
      __builtin_amdgcn_s_setprio(0);
      float sv[16];
#pragma unroll
      for (int r = 0; r < 16; ++r) sv[r] = sacc[r];
      if (k0 + 31 > q0w) {                   // diagonal region: causal mask
#pragma unroll
        for (int r = 0; r < 16; ++r)
          if (k0 + (r & 3) + 8 * (r >> 2) + 4 * hi > qg) sv[r] = -1e30f;
      }
      // ---- in-register online softmax with defer-max (THR=8, exp2 domain) ----
      float pmax = sv[0];
#pragma unroll
      for (int r = 1; r < 16; ++r) pmax = fmaxf(pmax, sv[r]);
      pmax = fmaxf(pmax, __shfl_xor(pmax, 32));
      float smax = pmax * SCALE2;
      if (!__all(smax - m <= 8.0f)) {
        float mnew = fmaxf(m, smax);
        float a = exp2f(m - mnew);
        l *= a;
#pragma unroll
        for (int db = 0; db < 4; ++db)
#pragma unroll
          for (int r = 0; r < 16; ++r) oacc[db][r] *= a;
        m = mnew;
      }
      float e[16]; float sum = 0.f;
#pragma unroll
      for (int r = 0; r < 16; ++r) { e[r] = exp2f(sv[r] * SCALE2 - m); sum += e[r]; }
      sum += __shfl_xor(sum, 32);
      l += sum;
      // ---- P -> bf16 PV B-fragments (4 half-swaps via shfl_xor 32) ----
      uint32_t pk[8];
#pragma unroll
      for (int i = 0; i < 8; ++i)
        pk[i] = (uint32_t)f2bf(e[2 * i]) | ((uint32_t)f2bf(e[2 * i + 1]) << 16);
      uint32_t sw[8];
#pragma unroll
      for (int i = 0; i < 8; ++i) sw[i] = (uint32_t)__shfl_xor((int)pk[i], 32);
      union { uint32_t u[4]; bf16x8 v; } p0, p1;
      p0.u[0] = hi ? sw[2] : pk[0];
      p0.u[1] = hi ? sw[3] : pk[1];
      p0.u[2] = hi ? pk[2] : sw[0];
      p0.u[3] = hi ? pk[3] : sw[1];
      p1.u[0] = hi ? sw[6] : pk[4];
      p1.u[1] = hi ? sw[7] : pk[5];
      p1.u[2] = hi ? pk[6] : sw[4];
      p1.u[3] = hi ? pk[7] : sw[5];
      // ---- PV: O^T[d][q] += V^T[d][k] P^T[k][q] ----
      __builtin_amdgcn_s_setprio(1);
#pragma unroll
      for (int db = 0; db < 4; ++db) {
        bf16x8 vf0 = *(const bf16x8*)(VB + (32 * db + lq) * 40 + ((hi ^ kx) << 3));
        bf16x8 vf1 = *(const bf16x8*)(VB + (32 * db + lq) * 40 + (((2 + hi) ^ kx) << 3));
        oacc[db] = __builtin_amdgcn_mfma_f32_32x32x16_bf16(vf0, p0.v, oacc[db], 0, 0, 0);
        oacc[db] = __builtin_amdgcn_mfma_f32_32x32x16_bf16(vf1, p1.v, oacc[db], 0, 0, 0);
      }
      __builtin_amdgcn_s_setprio(0);
    }
    asm volatile("s_waitcnt vmcnt(0) lgkmcnt(0)" ::: "memory");
    __syncthreads();
    cur ^= 1;
  }

  // ---- epilogue: normalize + store (pairs of consecutive d as u32) ----
  float inv = 1.f / l;
  ushort* op = aout + ((size_t)(b * 2048 + qg)) * 2048 + h * 128 + 4 * hi;
#pragma unroll
  for (int db = 0; db < 4; ++db)
#pragma unroll
    for (int i = 0; i < 8; ++i) {
      uint32_t u = (uint32_t)f2bf(oacc[db][2 * i] * inv) |
                   ((uint32_t)f2bf(oacc[db][2 * i + 1] * inv) << 16);
      int dbase = 32 * db + (i & 1) * 2 + (i >> 1) * 8;
      *(uint32_t*)(op + dbase) = u;
    }
}

// ---------------- launcher ----------------
extern "C" void kernel_launch(void* const* d_in, const int* in_sizes, int n_in,
                              void* d_out, int out_size, void* d_ws, size_t ws_size,
                              hipStream_t stream) {
  const float* x = (const float*)d_in[0];
  const float* fcos = (const float*)d_in[1];
  const float* fsin = (const float*)d_in[2];
  const float* wq_a = (const float*)d_in[3];
  const float* qnw = (const float*)d_in[4];
  const float* wq_b = (const float*)d_in[5];
  const float* wkv_a = (const float*)d_in[6];
  const float* kvnw = (const float*)d_in[7];
  const float* wkv_b = (const float*)d_in[8];
  const float* wo = (const float*)d_in[9];
  float* out = (float*)d_out;

  char* ws = (char*)d_ws;
  size_t off = 0;
  auto alloc = [&](size_t bytes) -> char* {
    char* p = ws + off;
    off += (bytes + 255) & ~(size_t)255;
    return p;
  };
  ushort* xb     = (ushort*)alloc(4096ull * 2048 * 2);
  ushort* wqa_t  = (ushort*)alloc(1536ull * 2048 * 2);   // } these three (18.3MB)
  ushort* wqb_t  = (ushort*)alloc(3072ull * 1536 * 2);   // } are dead after GEMM2
  ushort* wkva_t = (ushort*)alloc(640ull * 2048 * 2);    // } -> reused as vT (16.8MB)
  ushort* wkvb_t = (ushort*)alloc(4096ull * 512 * 2);
  ushort* wo_t   = (ushort*)alloc(2048ull * 2048 * 2);
  float*  cq     = (float*)alloc(4096ull * 1536 * 4);
  float*  ckv    = (float*)alloc(4096ull * 576 * 4);
  ushort* cqn    = (ushort*)alloc(4096ull * 1536 * 2);
  ushort* ckvn   = (ushort*)alloc(4096ull * 512 * 2);
  ushort* kbuf   = (ushort*)alloc(2ull * 16 * 2048 * 192 * 2);
  ushort* qbuf   = (ushort*)cq;     // reuse: cq dead after rmsnorm (25.2MB each)
  ushort* aout   = xb;              // reuse: x dead after GEMM1a/1b
  ushort* vT     = wqa_t;           // reuse: wqa_t+wqb_t+wkva_t dead after GEMM2

  dim3 tb(32, 8);
  k_f32_to_bf16<<<2048, 256, 0, stream>>>(x, xb, 4096 * 2048 / 4);
  k_transpose_f32_bf16<<<dim3(48, 64), tb, 0, stream>>>(wq_a, wqa_t, 2048, 1536);
  k_transpose_f32_bf16<<<dim3(18, 64), tb, 0, stream>>>(wkv_a, wkva_t, 2048, 576);
  k_transpose_f32_bf16<<<dim3(96, 48), tb, 0, stream>>>(wq_b, wqb_t, 1536, 3072);
  k_transpose_f32_bf16<<<dim3(128, 16), tb, 0, stream>>>(wkv_b, wkvb_t, 512, 4096);
  k_transpose_f32_bf16<<<dim3(64, 64), tb, 0, stream>>>(wo, wo_t, 2048, 2048);

  // cq = xb @ wq_a  (M=4096, K=2048, N=1536)
  k_gemm<float><<<dim3(12, 32), 256, 0, stream>>>(xb, wqa_t, cq, 2048, 1536);
  // ckv = xb @ wkv_a (N padded 640, Nreal=576)
  k_gemm<float><<<dim3(5, 32), 256, 0, stream>>>(xb, wkva_t, ckv, 2048, 576);

  k_rmsnorm_bf16<<<4096, 256, 0, stream>>>(cq, qnw, cqn, 1536);
  k_kvnorm_rope<<<4096, 256, 0, stream>>>(ckv, kvnw, fcos, fsin, ckvn, kbuf);

  // q = cqn @ wq_b (K=1536, N=3072), bf16 out  (last reader of wqb_t)
  k_gemm<ushort><<<dim3(24, 32), 256, 0, stream>>>(cqn, wqb_t, qbuf, 1536, 3072);
  k_qrope<<<4096, 256, 0, stream>>>(qbuf, fcos, fsin);

  // kv = ckvn @ wkv_b (K=512, N=4096) -> kbuf (nope) + vT (V transposed)
  k_gemm_kv<<<dim3(32, 32), 256, 0, stream>>>(ckvn, wkvb_t, kbuf, vT, 512);

  k_attn7<<<dim3(512), 256, 0, stream>>>(qbuf, kbuf, vT, aout);

  // out = aout @ wo (K=2048, N=2048), fp32 out
  k_gemm<float><<<dim3(16, 32), 256, 0, stream>>>(aout, wo_t, out, 2048, 2048);
}

// Round 8
// 428.102 us; speedup vs baseline: 1.1633x; 1.0028x over previous
//
#include <hip/hip_runtime.h>
#include <cstdint>
#include <cstddef>

// ---------------- common types / helpers ----------------
typedef __attribute__((ext_vector_type(8))) short bf16x8;
typedef __attribute__((ext_vector_type(4))) float f32x4;
typedef __attribute__((ext_vector_type(16))) float f32x16;

#define S_LEN 2048
#define SCALE2 0.10411754f   // 192^-0.5 * log2(e)

__device__ __forceinline__ ushort f2bf(float f) {
  uint32_t u = __float_as_uint(f);
  u = (u + 0x7FFFu + ((u >> 16) & 1u)) >> 16;
  return (ushort)u;
}
__device__ __forceinline__ float bf2f(ushort u) {
  return __uint_as_float(((uint32_t)u) << 16);
}

typedef __attribute__((address_space(1))) void GV;
typedef __attribute__((address_space(3))) void LV;
__device__ __forceinline__ void gload16(const void* g, void* l) {
  __builtin_amdgcn_global_load_lds((GV*)g, (LV*)l, 16, 0, 0);
}

__device__ __forceinline__ void store_out(float* p, float v) { *p = v; }
__device__ __forceinline__ void store_out(ushort* p, float v) { *p = f2bf(v); }

// ---------------- fp32 -> bf16 convert ----------------
__global__ void k_f32_to_bf16(const float* __restrict__ in, ushort* __restrict__ out, int n4) {
  int i = blockIdx.x * blockDim.x + threadIdx.x;
  int stride = gridDim.x * blockDim.x;
  for (; i < n4; i += stride) {
    float4 v = reinterpret_cast<const float4*>(in)[i];
    ushort4 o;
    o.x = f2bf(v.x); o.y = f2bf(v.y); o.z = f2bf(v.z); o.w = f2bf(v.w);
    reinterpret_cast<ushort4*>(out)[i] = o;
  }
}

// ---------------- fp32 (R,C) -> bf16 transposed (C,R) ----------------
__global__ void k_transpose_f32_bf16(const float* __restrict__ in, ushort* __restrict__ out,
                                     int R, int C) {
  __shared__ float tile[32][33];
  int c0 = blockIdx.x * 32, r0 = blockIdx.y * 32;
  int tx = threadIdx.x, ty = threadIdx.y;
#pragma unroll
  for (int i = 0; i < 32; i += 8) {
    int r = r0 + ty + i, c = c0 + tx;
    if (r < R && c < C) tile[ty + i][tx] = in[(size_t)r * C + c];
  }
  __syncthreads();
#pragma unroll
  for (int i = 0; i < 32; i += 8) {
    int c = c0 + ty + i, r = r0 + tx;
    if (r < R && c < C) out[(size_t)c * R + r] = f2bf(tile[tx][ty + i]);
  }
}

// ---------------- bf16 GEMM: C[M,Nreal] = A[M,K] * Bt[N,K]^T ----------------
template <typename OUT>
__global__ __launch_bounds__(256) void k_gemm(const ushort* __restrict__ A,
                                              const ushort* __restrict__ Bt,
                                              OUT* __restrict__ C, int K, int Nreal) {
  __shared__ ushort As[128 * 32];
  __shared__ ushort Bs[128 * 32];
  const int t = threadIdx.x, lane = t & 63, w = t >> 6;
  // XCD-aware bijective swizzle (nwg % 8 == 0 for all our grids)
  const int nwg = gridDim.x * gridDim.y;
  const int wg = blockIdx.y * gridDim.x + blockIdx.x;
  const int swz = (wg & 7) * (nwg >> 3) + (wg >> 3);
  const int m0 = (swz / gridDim.x) * 128, n0 = (swz % gridDim.x) * 128;
  const int wm = (w >> 1) * 64, wn = (w & 1) * 64;
  const int g = lane >> 4, q = lane & 15;
  f32x4 acc[4][4] = {};
  for (int kt = 0; kt < K; kt += 32) {
#pragma unroll
    for (int i = 0; i < 2; i++) {
      int idx = i * 256 + t;
      gload16(A + (size_t)(m0 + (idx >> 2)) * K + kt + (idx & 3) * 8,
              (char*)As + (size_t)(i * 256 + (w << 6)) * 16);
      gload16(Bt + (size_t)(n0 + (idx >> 2)) * K + kt + (idx & 3) * 8,
              (char*)Bs + (size_t)(i * 256 + (w << 6)) * 16);
    }
    __syncthreads();
    bf16x8 af[4], bfr[4];
#pragma unroll
    for (int mi = 0; mi < 4; mi++) af[mi] = *(const bf16x8*)(As + (wm + 16 * mi + q) * 32 + 8 * g);
#pragma unroll
    for (int ni = 0; ni < 4; ni++) bfr[ni] = *(const bf16x8*)(Bs + (wn + 16 * ni + q) * 32 + 8 * g);
#pragma unroll
    for (int mi = 0; mi < 4; mi++)
#pragma unroll
      for (int ni = 0; ni < 4; ni++)
        acc[mi][ni] = __builtin_amdgcn_mfma_f32_16x16x32_bf16(af[mi], bfr[ni], acc[mi][ni], 0, 0, 0);
    __syncthreads();
  }
#pragma unroll
  for (int mi = 0; mi < 4; mi++)
#pragma unroll
    for (int ni = 0; ni < 4; ni++) {
      int col = n0 + wn + 16 * ni + q;
      if (col < Nreal) {
        int row = m0 + wm + 16 * mi + 4 * g;
#pragma unroll
        for (int r = 0; r < 4; r++)
          store_out(&C[(size_t)(row + r) * Nreal + col], acc[mi][ni][r]);
      }
    }
}

// ---------------- kv GEMM: writes k_nope into kbuf[b][h][s][192] cols 0..127
// and V into vT[b][h][d][2048]. M=4096 tokens, K=512, N=4096. ----------------
__global__ __launch_bounds__(256) void k_gemm_kv(const ushort* __restrict__ A,
                                                 const ushort* __restrict__ Bt,
                                                 ushort* __restrict__ kbuf,
                                                 ushort* __restrict__ vT, int K) {
  __shared__ ushort As[128 * 32];
  __shared__ ushort Bs[128 * 32];
  const int t = threadIdx.x, lane = t & 63, w = t >> 6;
  const int nwg = gridDim.x * gridDim.y;
  const int wg = blockIdx.y * gridDim.x + blockIdx.x;
  const int swz = (wg & 7) * (nwg >> 3) + (wg >> 3);
  const int m0 = (swz / gridDim.x) * 128, n0 = (swz % gridDim.x) * 128;
  const int wm = (w >> 1) * 64, wn = (w & 1) * 64;
  const int g = lane >> 4, q = lane & 15;
  f32x4 acc[4][4] = {};
  for (int kt = 0; kt < K; kt += 32) {
#pragma unroll
    for (int i = 0; i < 2; i++) {
      int idx = i * 256 + t;
      gload16(A + (size_t)(m0 + (idx >> 2)) * K + kt + (idx & 3) * 8,
              (char*)As + (size_t)(i * 256 + (w << 6)) * 16);
      gload16(Bt + (size_t)(n0 + (idx >> 2)) * K + kt + (idx & 3) * 8,
              (char*)Bs + (size_t)(i * 256 + (w << 6)) * 16);
    }
    __syncthreads();
    bf16x8 af[4], bfr[4];
#pragma unroll
    for (int mi = 0; mi < 4; mi++) af[mi] = *(const bf16x8*)(As + (wm + 16 * mi + q) * 32 + 8 * g);
#pragma unroll
    for (int ni = 0; ni < 4; ni++) bfr[ni] = *(const bf16x8*)(Bs + (wn + 16 * ni + q) * 32 + 8 * g);
#pragma unroll
    for (int mi = 0; mi < 4; mi++)
#pragma unroll
      for (int ni = 0; ni < 4; ni++)
        acc[mi][ni] = __builtin_amdgcn_mfma_f32_16x16x32_bf16(af[mi], bfr[ni], acc[mi][ni], 0, 0, 0);
    __syncthreads();
  }
#pragma unroll
  for (int mi = 0; mi < 4; mi++)
#pragma unroll
    for (int ni = 0; ni < 4; ni++) {
      int col = n0 + wn + 16 * ni + q;     // 0..4095
      int hh = col >> 8, jj = col & 255;
      int row0 = m0 + wm + 16 * mi + 4 * g;
#pragma unroll
      for (int r = 0; r < 4; r++) {
        int tok = row0 + r;
        int bb = tok >> 11, ss = tok & 2047;
        ushort v = f2bf(acc[mi][ni][r]);
        if (jj < 128)
          kbuf[((size_t)(bb * 16 + hh) * 2048 + ss) * 192 + jj] = v;
        else
          vT[((size_t)(bb * 16 + hh) * 128 + (jj - 128)) * 2048 + ss] = v;
      }
    }
}

// ---------------- RMSNorm (fp32 in, bf16 out) ----------------
__global__ void k_rmsnorm_bf16(const float* __restrict__ in, const float* __restrict__ w,
                               ushort* __restrict__ out, int D) {
  int row = blockIdx.x;
  const float* x = in + (size_t)row * D;
  ushort* o = out + (size_t)row * D;
  float ss = 0.f;
  for (int i = threadIdx.x; i < D; i += 256) { float v = x[i]; ss += v * v; }
#pragma unroll
  for (int m = 1; m < 64; m <<= 1) ss += __shfl_xor(ss, m);
  __shared__ float red[4];
  if ((threadIdx.x & 63) == 0) red[threadIdx.x >> 6] = ss;
  __syncthreads();
  float tot = red[0] + red[1] + red[2] + red[3];
  float sc = rsqrtf(tot / (float)D + 1e-6f);
  for (int i = threadIdx.x; i < D; i += 256) o[i] = f2bf(x[i] * sc * w[i]);
}

// ---------------- kv RMSNorm (512) + k_pe rope broadcast into kbuf ----------------
__global__ void k_kvnorm_rope(const float* __restrict__ ckv, const float* __restrict__ w,
                              const float* __restrict__ cosT, const float* __restrict__ sinT,
                              ushort* __restrict__ ckvn, ushort* __restrict__ kbuf) {
  int tok = blockIdx.x, b = tok >> 11, s = tok & 2047;
  const float* x = ckv + (size_t)tok * 576;
  float ss = 0.f;
  for (int i = threadIdx.x; i < 512; i += 256) { float v = x[i]; ss += v * v; }
#pragma unroll
  for (int m = 1; m < 64; m <<= 1) ss += __shfl_xor(ss, m);
  __shared__ float red[4];
  if ((threadIdx.x & 63) == 0) red[threadIdx.x >> 6] = ss;
  __syncthreads();
  float tot = red[0] + red[1] + red[2] + red[3];
  float sc = rsqrtf(tot / 512.f + 1e-6f);
  for (int i = threadIdx.x; i < 512; i += 256) ckvn[(size_t)tok * 512 + i] = f2bf(x[i] * sc * w[i]);
  if (threadIdx.x < 32) {
    int i = threadIdx.x;
    float xr = x[512 + 2 * i], xi = x[512 + 2 * i + 1];
    float c = cosT[s * 32 + i], sn = sinT[s * 32 + i];
    uint32_t lo = f2bf(xr * c - xi * sn);
    uint32_t hi = f2bf(xr * sn + xi * c);
    uint32_t pk = lo | (hi << 16);
#pragma unroll
    for (int h = 0; h < 16; ++h)
      *(uint32_t*)(kbuf + ((size_t)(b * 16 + h) * 2048 + s) * 192 + 128 + 2 * i) = pk;
  }
}

// ---------------- q rope, in-place on bf16 q (4096, 16, 192) ----------------
__global__ void k_qrope(ushort* __restrict__ qb, const float* __restrict__ cosT,
                        const float* __restrict__ sinT) {
  int tok = blockIdx.x, s = tok & (S_LEN - 1);
  for (int pp = threadIdx.x; pp < 512; pp += 256) {
    int h = pp >> 5, i = pp & 31;
    ushort* base = qb + ((size_t)tok * 16 + h) * 192 + 128;
    float xr = bf2f(base[2 * i]), xi = bf2f(base[2 * i + 1]);
    float c = cosT[s * 32 + i], sn = sinT[s * 32 + i];
    base[2 * i] = f2bf(xr * c - xi * sn);
    base[2 * i + 1] = f2bf(xr * sn + xi * c);
  }
}

// ---------------- causal flash attention: swapped-QK^T, 32x32 MFMA ----------------
// grid 512 (1-D), 4 waves/block, 2 blocks/CU. Block id: qt = 15-(id>>5)
// (heavy tiles dispatch first), bh = id&31.
// NEW (R8): 3-buffer staging, 2 tiles ahead, counted vmcnt (T4).
//  - staging flattened to 24 slots (K 13 + V 10 + 1 dup) = exactly 6
//    global_load_lds per wave per stage;
//  - iter k: s_waitcnt vmcnt(6)  [own stage-k loads landed; stage-k+1 in
//    flight]  ->  RAW s_barrier (NOT __syncthreads -- that re-inserts a
//    vmcnt(0) drain)  ->  compute(k)  ->  issue stage(k+2);
//  - last iter waits vmcnt(0).
// Safety: every ds_read has a dependent MFMA before the barrier (compiler
// lgkm waits), and no wave can run >1 compute-phase ahead, so stage(k+2)
// never overwrites a buffer still being read. global_load_lds is NOT drained
// by __syncthreads (R2 failure / R4 fix evidence) -- the explicit per-wave
// vmcnt-before-barrier is what makes cross-wave LDS staging sound.
__global__ __launch_bounds__(256, 2) void k_attn8(const ushort* __restrict__ qb,
                                                  const ushort* __restrict__ kb,
                                                  const ushort* __restrict__ vT,
                                                  ushort* __restrict__ aout) {
  const int id = blockIdx.x;
  const int qt = 15 - (id >> 5);
  const int bh = id & 31;
  const int h = bh & 15, b = bh >> 4;

  const int t = threadIdx.x, lane = t & 63, w = t >> 6;
  const int lq = lane & 31, hi = lane >> 5;
  const int kx = (lq >> 3) & 3;              // read-side chunk XOR

  __shared__ ushort Ks[3][6656];   // 32 rows x 25 chunks (1 pad chunk/row) + tail
  __shared__ ushort Vs[3][5120];   // 128 rows x 5 chunks (1 pad chunk/row)

  const ushort* kh = kb + (size_t)(b * 16 + h) * (2048 * 192);
  const ushort* vh = vT + (size_t)(b * 16 + h) * (128 * 2048);

  // 24 staging slots: 0..12 = K (13 x 1KB), 13..22 = V (10 x 1KB), 23 = dup of 22.
  // Each wave does slots {w, 4+w, ..., 20+w} -> exactly 6 loads/wave/stage.
  auto stage = [&](int k0, int bi) {
    char* kbase = (char*)&Ks[bi][0];
    char* vbase = (char*)&Vs[bi][0];
#pragma unroll
    for (int it = 0; it < 6; ++it) {
      int ii = it * 4 + w;
      if (ii > 22) ii = 22;                  // slot 23: duplicate of 22 (same src+dst, benign)
      if (ii < 13) {
        unsigned s = ii * 64 + lane;
        int r = s / 25, cs = s - r * 25;
        if (r > 31) { r = 31; cs = 24; }
        int cg = cs ^ ((r >> 3) & 3);        // inverse-swizzled source chunk
        if (cg > 23) cg = 0;                 // pad slots load dummy
        gload16(kh + (size_t)(k0 + r) * 192 + cg * 8, kbase + ii * 1024);
      } else {
        int jj = ii - 13;
        unsigned s = jj * 64 + lane;
        int r = s / 5, cs = s - r * 5;
        int cg = cs ^ ((r >> 3) & 3);
        if (cg > 3) cg = 0;
        gload16(vh + (size_t)r * 2048 + k0 + cg * 8, vbase + jj * 1024);
      }
    }
  };

  const int q0 = qt * 128;
  const int q0w = q0 + 32 * w;               // wave's lowest q-row
  const int qg = q0w + lq;                   // this lane's q-row
  const int nkt = qt * 4 + 4;

  // Q fragments: lane reads its q-row, d = 16s + 8*hi .. +7
  bf16x8 qf[12];
  {
    const ushort* qp = qb + ((size_t)(b * 2048 + qg) * 16 + h) * 192 + 8 * hi;
#pragma unroll
    for (int s = 0; s < 12; ++s) qf[s] = *(const bf16x8*)(qp + 16 * s);
  }

  f32x16 oacc[4];
#pragma unroll
  for (int db = 0; db < 4; ++db)
#pragma unroll
    for (int r = 0; r < 16; ++r) oacc[db][r] = 0.f;
  float m = -1e30f, l = 0.f;

  stage(0, 0);
  stage(32, 1);                              // nkt >= 4 always

  for (int kt = 0; kt < nkt; ++kt) {
    const int k0 = kt * 32;
    const int bi = kt % 3;
    if (kt + 1 < nkt) asm volatile("s_waitcnt vmcnt(6)" ::: "memory");
    else              asm volatile("s_waitcnt vmcnt(0)" ::: "memory");
    __builtin_amdgcn_s_barrier();
    const ushort* KB = &Ks[bi][0];
    const ushort* VB = &Vs[bi][0];
    if (k0 <= q0w + 31) {
      // ---- QK^T (swapped): S[kk][q] over d=192 in 12 slabs ----
      f32x16 sacc;
#pragma unroll
      for (int r = 0; r < 16; ++r) sacc[r] = 0.f;
      __builtin_amdgcn_s_setprio(1);
#pragma unroll
      for (int s = 0; s < 12; ++s) {
        bf16x8 kf = *(const bf16x8*)(KB + lq * 200 + (((2 * s + hi) ^ kx) << 3));
        sacc = __builtin_amdgcn_mfma_f32_32x32x16_bf16(kf, qf[s], sacc, 0, 0, 0);
      }
      __builtin_amdgcn_s_setprio(0);
      float sv[16];
#pragma unroll
      for (int r = 0; r < 16; ++r) sv[r] = sacc[r];
      if (k0 + 31 > q0w) {                   // diagonal region: causal mask
#pragma unroll
        for (int r = 0; r < 16; ++r)
          if (k0 + (r & 3) + 8 * (r >> 2) + 4 * hi > qg) sv[r] = -1e30f;
      }
      // ---- in-register online softmax with defer-max (THR=8, exp2 domain) ----
      float pmax = sv[0];
#pragma unroll
      for (int r = 1; r < 16; ++r) pmax = fmaxf(pmax, sv[r]);
      pmax = fmaxf(pmax, __shfl_xor(pmax, 32));
      float smax = pmax * SCALE2;
      if (!__all(smax - m <= 8.0f)) {
        float mnew = fmaxf(m, smax);
        float a = exp2f(m - mnew);
        l *= a;
#pragma unroll
        for (int db = 0; db < 4; ++db)
#pragma unroll
          for (int r = 0; r < 16; ++r) oacc[db][r] *= a;
        m = mnew;
      }
      float e[16]; float sum = 0.f;
#pragma unroll
      for (int r = 0; r < 16; ++r) { e[r] = exp2f(sv[r] * SCALE2 - m); sum += e[r]; }
      sum += __shfl_xor(sum, 32);
      l += sum;
      // ---- P -> bf16 PV B-fragments (4 half-swaps via shfl_xor 32) ----
      uint32_t pk[8];
#pragma unroll
      for (int i = 0; i < 8; ++i)
        pk[i] = (uint32_t)f2bf(e[2 * i]) | ((uint32_t)f2bf(e[2 * i + 1]) << 16);
      uint32_t sw[8];
#pragma unroll
      for (int i = 0; i < 8; ++i) sw[i] = (uint32_t)__shfl_xor((int)pk[i], 32);
      union { uint32_t u[4]; bf16x8 v; } p0, p1;
      p0.u[0] = hi ? sw[2] : pk[0];
      p0.u[1] = hi ? sw[3] : pk[1];
      p0.u[2] = hi ? pk[2] : sw[0];
      p0.u[3] = hi ? pk[3] : sw[1];
      p1.u[0] = hi ? sw[6] : pk[4];
      p1.u[1] = hi ? sw[7] : pk[5];
      p1.u[2] = hi ? pk[6] : sw[4];
      p1.u[3] = hi ? pk[7] : sw[5];
      // ---- PV: O^T[d][q] += V^T[d][k] P^T[k][q] ----
      __builtin_amdgcn_s_setprio(1);
#pragma unroll
      for (int db = 0; db < 4; ++db) {
        bf16x8 vf0 = *(const bf16x8*)(VB + (32 * db + lq) * 40 + ((hi ^ kx) << 3));
        bf16x8 vf1 = *(const bf16x8*)(VB + (32 * db + lq) * 40 + (((2 + hi) ^ kx) << 3));
        oacc[db] = __builtin_amdgcn_mfma_f32_32x32x16_bf16(vf0, p0.v, oacc[db], 0, 0, 0);
        oacc[db] = __builtin_amdgcn_mfma_f32_32x32x16_bf16(vf1, p1.v, oacc[db], 0, 0, 0);
      }
      __builtin_amdgcn_s_setprio(0);
    }
    if (kt + 2 < nkt) stage((kt + 2) * 32, (kt + 2) % 3);
  }

  // ---- epilogue: normalize + store (pairs of consecutive d as u32) ----
  float inv = 1.f / l;
  ushort* op = aout + ((size_t)(b * 2048 + qg)) * 2048 + h * 128 + 4 * hi;
#pragma unroll
  for (int db = 0; db < 4; ++db)
#pragma unroll
    for (int i = 0; i < 8; ++i) {
      uint32_t u = (uint32_t)f2bf(oacc[db][2 * i] * inv) |
                   ((uint32_t)f2bf(oacc[db][2 * i + 1] * inv) << 16);
      int dbase = 32 * db + (i & 1) * 2 + (i >> 1) * 8;
      *(uint32_t*)(op + dbase) = u;
    }
}

// ---------------- launcher ----------------
extern "C" void kernel_launch(void* const* d_in, const int* in_sizes, int n_in,
                              void* d_out, int out_size, void* d_ws, size_t ws_size,
                              hipStream_t stream) {
  const float* x = (const float*)d_in[0];
  const float* fcos = (const float*)d_in[1];
  const float* fsin = (const float*)d_in[2];
  const float* wq_a = (const float*)d_in[3];
  const float* qnw = (const float*)d_in[4];
  const float* wq_b = (const float*)d_in[5];
  const float* wkv_a = (const float*)d_in[6];
  const float* kvnw = (const float*)d_in[7];
  const float* wkv_b = (const float*)d_in[8];
  const float* wo = (const float*)d_in[9];
  float* out = (float*)d_out;

  char* ws = (char*)d_ws;
  size_t off = 0;
  auto alloc = [&](size_t bytes) -> char* {
    char* p = ws + off;
    off += (bytes + 255) & ~(size_t)255;
    return p;
  };
  ushort* xb     = (ushort*)alloc(4096ull * 2048 * 2);
  ushort* wqa_t  = (ushort*)alloc(1536ull * 2048 * 2);   // } these three (18.3MB)
  ushort* wqb_t  = (ushort*)alloc(3072ull * 1536 * 2);   // } are dead after GEMM2
  ushort* wkva_t = (ushort*)alloc(640ull * 2048 * 2);    // } -> reused as vT (16.8MB)
  ushort* wkvb_t = (ushort*)alloc(4096ull * 512 * 2);
  ushort* wo_t   = (ushort*)alloc(2048ull * 2048 * 2);
  float*  cq     = (float*)alloc(4096ull * 1536 * 4);
  float*  ckv    = (float*)alloc(4096ull * 576 * 4);
  ushort* cqn    = (ushort*)alloc(4096ull * 1536 * 2);
  ushort* ckvn   = (ushort*)alloc(4096ull * 512 * 2);
  ushort* kbuf   = (ushort*)alloc(2ull * 16 * 2048 * 192 * 2);
  ushort* qbuf   = (ushort*)cq;     // reuse: cq dead after rmsnorm (25.2MB each)
  ushort* aout   = xb;              // reuse: x dead after GEMM1a/1b
  ushort* vT     = wqa_t;           // reuse: wqa_t+wqb_t+wkva_t dead after GEMM2

  dim3 tb(32, 8);
  k_f32_to_bf16<<<2048, 256, 0, stream>>>(x, xb, 4096 * 2048 / 4);
  k_transpose_f32_bf16<<<dim3(48, 64), tb, 0, stream>>>(wq_a, wqa_t, 2048, 1536);
  k_transpose_f32_bf16<<<dim3(18, 64), tb, 0, stream>>>(wkv_a, wkva_t, 2048, 576);
  k_transpose_f32_bf16<<<dim3(96, 48), tb, 0, stream>>>(wq_b, wqb_t, 1536, 3072);
  k_transpose_f32_bf16<<<dim3(128, 16), tb, 0, stream>>>(wkv_b, wkvb_t, 512, 4096);
  k_transpose_f32_bf16<<<dim3(64, 64), tb, 0, stream>>>(wo, wo_t, 2048, 2048);

  // cq = xb @ wq_a  (M=4096, K=2048, N=1536)
  k_gemm<float><<<dim3(12, 32), 256, 0, stream>>>(xb, wqa_t, cq, 2048, 1536);
  // ckv = xb @ wkv_a (N padded 640, Nreal=576)
  k_gemm<float><<<dim3(5, 32), 256, 0, stream>>>(xb, wkva_t, ckv, 2048, 576);

  k_rmsnorm_bf16<<<4096, 256, 0, stream>>>(cq, qnw, cqn, 1536);
  k_kvnorm_rope<<<4096, 256, 0, stream>>>(ckv, kvnw, fcos, fsin, ckvn, kbuf);

  // q = cqn @ wq_b (K=1536, N=3072), bf16 out  (last reader of wqb_t)
  k_gemm<ushort><<<dim3(24, 32), 256, 0, stream>>>(cqn, wqb_t, qbuf, 1536, 3072);
  k_qrope<<<4096, 256, 0, stream>>>(qbuf, fcos, fsin);

  // kv = ckvn @ wkv_b (K=512, N=4096) -> kbuf (nope) + vT (V transposed)
  k_gemm_kv<<<dim3(32, 32), 256, 0, stream>>>(ckvn, wkvb_t, kbuf, vT, 512);

  k_attn8<<<dim3(512), 256, 0, stream>>>(qbuf, kbuf, vT, aout);

  // out = aout @ wo (K=2048, N=2048), fp32 out
  k_gemm<float><<<dim3(16, 32), 256, 0, stream>>>(aout, wo_t, out, 2048, 2048);
}